// Round 1
// baseline (201944.983 us; speedup 1.0000x reference)
//
#include <hip/hip_runtime.h>

#define VOCAB 60
#define EMB   100
#define HID   100
#define SEQN  262144
#define NPROJ 300   // 3*HID

__device__ __forceinline__ float fast_sig(float x) {
    return __builtin_amdgcn_rcpf(1.0f + __builtin_amdgcn_exp2f(-1.442695041f * x));
}
__device__ __forceinline__ float fast_tanh(float x) {
    return 2.0f * __builtin_amdgcn_rcpf(1.0f + __builtin_amdgcn_exp2f(-2.885390082f * x)) - 1.0f;
}

// Precompute: proj[v][j] = emb[v]·w_ih[j] + b_ih[j] + (j<200 ? b_hh[j] : 0)
// and w_t[k][j] = w_hh[j][k] (transpose so the main kernel's weight load is coalesced).
__global__ void precompute_kernel(const float* __restrict__ emb,
                                  const float* __restrict__ w_ih,
                                  const float* __restrict__ b_ih,
                                  const float* __restrict__ b_hh,
                                  const float* __restrict__ w_hh,
                                  float* __restrict__ proj,
                                  float* __restrict__ w_t)
{
    int idx = blockIdx.x * blockDim.x + threadIdx.x;
    if (idx < VOCAB * NPROJ) {
        int v = idx / NPROJ, j = idx - v * NPROJ;
        float acc = b_ih[j] + (j < 2 * HID ? b_hh[j] : 0.0f);
        const float* er = emb  + v * EMB;
        const float* wr = w_ih + j * EMB;
        #pragma unroll 4
        for (int k = 0; k < EMB; ++k) acc = fmaf(er[k], wr[k], acc);
        proj[idx] = acc;
    }
    if (idx < NPROJ * HID) {
        int j = idx / HID, k = idx - j * HID;
        w_t[k * NPROJ + j] = w_hh[idx];
    }
}

// Single-workgroup sequential GRU. 320 threads = 5 waves on one CU.
// Thread j owns u[j] = W_hh[j]·h (weights in VGPRs). h in per-wave private LDS
// (broadcast float4 reads). One barrier per step; gate phase computed
// redundantly by every wave so h never crosses waves.
__global__ __launch_bounds__(320, 1) void gru_seq_kernel(
    const int*   __restrict__ x,
    const float* __restrict__ b_hh,
    const float* __restrict__ proj,
    const float* __restrict__ w_t,
    float* __restrict__ out)
{
    __shared__ float h_priv[5][128];
    __shared__ float u[2][320];

    const int tid  = threadIdx.x;
    const int wave = tid >> 6;
    const int lane = tid & 63;

    // Persistent weights: w[k] = w_hh[tid][k] via transposed table (coalesced).
    const int jj = (tid < NPROJ) ? tid : 0;
    float w[HID];
    #pragma unroll
    for (int k = 0; k < HID; ++k) w[k] = w_t[k * NPROJ + jj];

    // n-gate rows start their accumulator at b_hn (it sits inside r*(...)).
    const float bhn  = (tid >= 2 * HID && tid < NPROJ) ? b_hh[tid] : 0.0f;
    const bool  isRZ = (tid < 2 * HID);

    h_priv[wave][lane]      = 0.0f;
    h_priv[wave][lane + 64] = 0.0f;
    float hold0 = 0.0f, hold1 = 0.0f;

    const int  jb1 = (lane < HID - 64) ? (lane + 64) : (HID - 64 - 1); // clamp reads
    const bool b1v = (lane < HID - 64);                                 // lanes 0..35

    // Software-pipelined token / proj lookups (one step of slack each).
    int tok_next = x[0];
    float xpA = isRZ ? proj[tok_next * NPROJ + jj] : bhn;
    float xn0 = proj[tok_next * NPROJ + 2 * HID + lane];
    float xn1 = proj[tok_next * NPROJ + 2 * HID + jb1];
    tok_next = x[1];

    __syncthreads();

    #pragma unroll 2
    for (int t = 0; t < SEQN; ++t) {
        // Prefetch for step t+1 (L2-resident, hidden under this step).
        int   tok_nn = x[(t + 2 < SEQN) ? (t + 2) : (SEQN - 1)];
        float xpA_n  = isRZ ? proj[tok_next * NPROJ + jj] : bhn;
        float xn0_n  = proj[tok_next * NPROJ + 2 * HID + lane];
        float xn1_n  = proj[tok_next * NPROJ + 2 * HID + jb1];

        // Phase A: u[j] = init + W_hh[j]·h   (h via b128 broadcast reads)
        float acc = xpA;
        const float* hp = h_priv[wave];
        #pragma unroll
        for (int k = 0; k < HID; k += 4) {
            float4 hv = *(const float4*)(hp + k);
            acc = fmaf(w[k],     hv.x, acc);
            acc = fmaf(w[k + 1], hv.y, acc);
            acc = fmaf(w[k + 2], hv.z, acc);
            acc = fmaf(w[k + 3], hv.w, acc);
        }
        u[t & 1][tid] = acc;
        __syncthreads();   // the ONLY barrier per step

        // Phase B (redundant in every wave): gates + h update, into own h copy.
        const float* ub = u[t & 1];
        float r0 = fast_sig(ub[lane]);
        float z0 = fast_sig(ub[lane + HID]);
        float n0 = fast_tanh(xn0 + r0 * ub[lane + 2 * HID]);
        float hn0 = n0 + z0 * (hold0 - n0);

        float r1 = fast_sig(ub[jb1]);
        float z1 = fast_sig(ub[jb1 + HID]);
        float n1 = fast_tanh(xn1 + r1 * ub[jb1 + 2 * HID]);
        float hn1 = n1 + z1 * (hold1 - n1);

        h_priv[wave][lane] = hn0;
        hold0 = hn0;
        if (b1v) { h_priv[wave][lane + 64] = hn1; hold1 = hn1; }

        tok_next = tok_nn;
        xpA = xpA_n; xn0 = xn0_n; xn1 = xn1_n;
    }

    if (wave == 0) {
        out[lane] = hold0;                  // h[0..63]
        if (b1v) out[lane + 64] = hold1;    // h[64..99]
    }
}

extern "C" void kernel_launch(void* const* d_in, const int* in_sizes, int n_in,
                              void* d_out, int out_size, void* d_ws, size_t ws_size,
                              hipStream_t stream)
{
    const int*   x    = (const int*)  d_in[0];
    const float* emb  = (const float*)d_in[1];
    const float* w_ih = (const float*)d_in[2];
    const float* w_hh = (const float*)d_in[3];
    const float* b_ih = (const float*)d_in[4];
    const float* b_hh = (const float*)d_in[5];
    float* out = (float*)d_out;

    // Workspace: proj table (60*300 f32 = 72 KB) + transposed w_hh (120 KB).
    float* proj = (float*)d_ws;
    float* w_t  = proj + VOCAB * NPROJ;

    const int total = NPROJ * HID;  // 30000 covers both precompute jobs
    precompute_kernel<<<(total + 255) / 256, 256, 0, stream>>>(
        emb, w_ih, b_ih, b_hh, w_hh, proj, w_t);
    gru_seq_kernel<<<1, 320, 0, stream>>>(x, b_hh, proj, w_t, out);
}